// Round 1
// baseline (1909.521 us; speedup 1.0000x reference)
//
#include <hip/hip_runtime.h>
#include <hip/hip_bf16.h>

#define NN   100000
#define EE   3200000
#define INF  512
#define HIDF 256
#define OUTF 64
#define KSTEPS 10

typedef __attribute__((ext_vector_type(8))) short short8;
typedef __attribute__((ext_vector_type(4))) float floatx4;

static __device__ inline short bf2s(__hip_bfloat16 h) {
    return __builtin_bit_cast(short, h);
}

// manual round-to-nearest-even f32 -> bf16 (finite inputs)
static __device__ inline short f2bf(float f) {
    unsigned u = __float_as_uint(f);
    unsigned r = (u + 0x7FFFu + ((u >> 16) & 1u)) >> 16;
    return (short)(unsigned short)r;
}

// ---------------- setup kernels ----------------

__global__ void zero_kernel(int* p, int n) {
    int i = blockIdx.x * 256 + threadIdx.x;
    if (i < n) p[i] = 0;
}

__global__ void count_kernel(const int* __restrict__ ei, int* __restrict__ counts) {
    int e = blockIdx.x * 256 + threadIdx.x;
    if (e < EE) atomicAdd(&counts[ei[EE + e]], 1);
}

__global__ void dinv_kernel(const int* __restrict__ counts, float* __restrict__ dinv) {
    int i = blockIdx.x * 256 + threadIdx.x;
    if (i < NN) dinv[i] = rsqrtf((float)(counts[i] + 1));  // +1 self loop
}

// chunk=256 exclusive scan, per-block
__global__ void scan1(const int* __restrict__ counts, int* __restrict__ offs,
                      int* __restrict__ partial) {
    __shared__ int s[256];
    int tid = threadIdx.x;
    int i = blockIdx.x * 256 + tid;
    int v = (i < NN) ? counts[i] : 0;
    s[tid] = v;
    __syncthreads();
    for (int d = 1; d < 256; d <<= 1) {
        int t = (tid >= d) ? s[tid - d] : 0;
        __syncthreads();
        s[tid] += t;
        __syncthreads();
    }
    if (i < NN) offs[i] = s[tid] - v;     // exclusive within block
    if (tid == 255) partial[blockIdx.x] = s[255];
}

__global__ void scan2(int* partial, int nblocks) {
    __shared__ int s[512];
    int tid = threadIdx.x;
    int v = (tid < nblocks) ? partial[tid] : 0;
    s[tid] = v;
    __syncthreads();
    for (int d = 1; d < 512; d <<= 1) {
        int t = (tid >= d) ? s[tid - d] : 0;
        __syncthreads();
        s[tid] += t;
        __syncthreads();
    }
    if (tid < nblocks) partial[tid] = s[tid] - v;  // exclusive block bases
}

__global__ void scan3(int* __restrict__ offs, const int* __restrict__ partial) {
    int i = blockIdx.x * 256 + threadIdx.x;
    if (i < NN) offs[i] += partial[i >> 8];
    else if (i == NN) offs[NN] = EE;
}

__global__ void fill_kernel(const int* __restrict__ ei, const int* __restrict__ offs,
                            int* __restrict__ cursor, const float* __restrict__ dinv,
                            uint2* __restrict__ packed) {
    int e = blockIdx.x * 256 + threadIdx.x;
    if (e >= EE) return;
    int r = ei[e];        // source (gathered from)
    int c = ei[EE + e];   // target (aggregated into)
    int pos = offs[c] + atomicAdd(&cursor[c], 1);
    float w = dinv[r] * dinv[c];
    packed[pos] = make_uint2((unsigned)r, __float_as_uint(w));
}

// pack W1 into per-lane MFMA B-fragment order:
// dst[((kk*16+t)*64 + q*16 + l)*8 + jj] = bf16(W1[kk*32+q*8+jj][t*16+l])
__global__ void pack_w1(const float* __restrict__ W1, short* __restrict__ W1p) {
    int id = blockIdx.x * 256 + threadIdx.x;
    if (id >= INF * HIDF) return;
    int jj = id & 7, l = (id >> 3) & 15, q = (id >> 7) & 3, t = (id >> 9) & 15, kk = id >> 13;
    int k = kk * 32 + q * 8 + jj, n = t * 16 + l;
    W1p[id] = f2bf(W1[k * HIDF + n]);
}

__global__ void pack_w2(const float* __restrict__ W2, short* __restrict__ W2p) {
    int id = blockIdx.x * 256 + threadIdx.x;
    if (id >= HIDF * OUTF) return;
    int jj = id & 7, l = (id >> 3) & 15, q = (id >> 7) & 3, t = (id >> 9) & 3, kk = id >> 11;
    int k = kk * 32 + q * 8 + jj, n = t * 16 + l;
    W2p[id] = f2bf(W2[k * OUTF + n]);
}

// ---------------- fused MLP: h = relu(x@W1+b1)@W2+b2 ; cur=h ; out=temp[0]*h ----

__global__ __launch_bounds__(256) void mlp_kernel(
    const float* __restrict__ x, const short* __restrict__ W1p,
    const short* __restrict__ W2p, const float* __restrict__ b1,
    const float* __restrict__ b2, const float* __restrict__ temp,
    float* __restrict__ cur, float* __restrict__ out) {

    __shared__ __align__(16) short hlds[64][HIDF + 8];

    int tid = threadIdx.x;
    int wave = tid >> 6, lane = tid & 63;
    int l16 = lane & 15, quad = lane >> 4;
    int brow = blockIdx.x * 64;

    const floatx4 zf = {0.f, 0.f, 0.f, 0.f};
    floatx4 acc[4][4];
#pragma unroll
    for (int mi = 0; mi < 4; mi++)
#pragma unroll
        for (int j = 0; j < 4; j++) acc[mi][j] = zf;

    // row base pointers (clamped for tail block; stores masked later)
    const float* rp[4];
#pragma unroll
    for (int mi = 0; mi < 4; mi++) {
        int row = brow + mi * 16 + l16;
        if (row > NN - 1) row = NN - 1;
        rp[mi] = x + (size_t)row * INF + quad * 8;
    }

    // GEMM1: rows [brow,brow+64) x cols [wave*64, wave*64+64), K=512
    for (int kk = 0; kk < 16; kk++) {
        short8 a[4];
#pragma unroll
        for (int mi = 0; mi < 4; mi++) {
            const float4* ap = reinterpret_cast<const float4*>(rp[mi] + kk * 32);
            float4 f0 = ap[0];
            float4 f1 = ap[1];
            __hip_bfloat162 q0 = __float22bfloat162_rn(make_float2(f0.x, f0.y));
            __hip_bfloat162 q1 = __float22bfloat162_rn(make_float2(f0.z, f0.w));
            __hip_bfloat162 q2 = __float22bfloat162_rn(make_float2(f1.x, f1.y));
            __hip_bfloat162 q3 = __float22bfloat162_rn(make_float2(f1.z, f1.w));
            short8 av;
            av[0] = bf2s(q0.x); av[1] = bf2s(q0.y);
            av[2] = bf2s(q1.x); av[3] = bf2s(q1.y);
            av[4] = bf2s(q2.x); av[5] = bf2s(q2.y);
            av[6] = bf2s(q3.x); av[7] = bf2s(q3.y);
            a[mi] = av;
        }
        short8 b[4];
#pragma unroll
        for (int j = 0; j < 4; j++) {
            int t = wave * 4 + j;
            b[j] = *reinterpret_cast<const short8*>(
                W1p + (((size_t)(kk * 16 + t) * 64 + quad * 16 + l16) << 3));
        }
#pragma unroll
        for (int mi = 0; mi < 4; mi++)
#pragma unroll
            for (int j = 0; j < 4; j++)
                acc[mi][j] = __builtin_amdgcn_mfma_f32_16x16x32_bf16(a[mi], b[j], acc[mi][j], 0, 0, 0);
    }

    // bias + relu -> LDS (bf16), C-layout: D[row=quad*4+r][col=l16]
#pragma unroll
    for (int j = 0; j < 4; j++) {
        float bj = b1[wave * 64 + j * 16 + l16];
#pragma unroll
        for (int mi = 0; mi < 4; mi++)
#pragma unroll
            for (int r = 0; r < 4; r++) {
                float v = acc[mi][j][r] + bj;
                v = fmaxf(v, 0.f);
                hlds[mi * 16 + quad * 4 + r][wave * 64 + j * 16 + l16] = f2bf(v);
            }
    }
    __syncthreads();

    // GEMM2: wave handles rows [wave*16, wave*16+16) x 64 out cols, K=256
    floatx4 acc2[4];
#pragma unroll
    for (int j = 0; j < 4; j++) acc2[j] = zf;

#pragma unroll
    for (int kk = 0; kk < 8; kk++) {
        short8 a2 = *reinterpret_cast<const short8*>(&hlds[wave * 16 + l16][kk * 32 + quad * 8]);
#pragma unroll
        for (int j = 0; j < 4; j++) {
            short8 bb = *reinterpret_cast<const short8*>(
                W2p + (((size_t)(kk * 4 + j) * 64 + quad * 16 + l16) << 3));
            acc2[j] = __builtin_amdgcn_mfma_f32_16x16x32_bf16(a2, bb, acc2[j], 0, 0, 0);
        }
    }

    float t0 = temp[0];
#pragma unroll
    for (int j = 0; j < 4; j++) {
        float bb = b2[j * 16 + l16];
#pragma unroll
        for (int r = 0; r < 4; r++) {
            int row = brow + wave * 16 + quad * 4 + r;
            if (row < NN) {
                float v = acc2[j][r] + bb;
                size_t o = (size_t)row * 64 + j * 16 + l16;
                cur[o] = v;
                out[o] = t0 * v;
            }
        }
    }
}

// ---------------- propagation: one wave per target node, lane = feature ------

__global__ __launch_bounds__(256) void prop_kernel(
    const uint2* __restrict__ packed, const int* __restrict__ offs,
    const float* __restrict__ dinv, const float* __restrict__ cur,
    float* __restrict__ nxt, float* __restrict__ hid,
    const float* __restrict__ temp, int k) {

    int node = blockIdx.x * 4 + (threadIdx.x >> 6);
    if (node >= NN) return;
    int f = threadIdx.x & 63;
    float g = temp[k];
    int beg = offs[node], end = offs[node + 1];
    float dv = dinv[node];
    size_t o = (size_t)node * 64 + f;
    float acc = dv * dv * cur[o];   // self loop

    int e = beg;
    for (; e + 4 <= end; e += 4) {
        uint2 p0 = packed[e];
        uint2 p1 = packed[e + 1];
        uint2 p2 = packed[e + 2];
        uint2 p3 = packed[e + 3];
        float v0 = cur[(size_t)p0.x * 64 + f];
        float v1 = cur[(size_t)p1.x * 64 + f];
        float v2 = cur[(size_t)p2.x * 64 + f];
        float v3 = cur[(size_t)p3.x * 64 + f];
        acc += __uint_as_float(p0.y) * v0;
        acc += __uint_as_float(p1.y) * v1;
        acc += __uint_as_float(p2.y) * v2;
        acc += __uint_as_float(p3.y) * v3;
    }
    for (; e < end; ++e) {
        uint2 p = packed[e];
        acc += __uint_as_float(p.y) * cur[(size_t)p.x * 64 + f];
    }

    nxt[o] = acc;
    hid[o] += g * acc;
}

// ---------------- launch ----------------

extern "C" void kernel_launch(void* const* d_in, const int* in_sizes, int n_in,
                              void* d_out, int out_size, void* d_ws, size_t ws_size,
                              hipStream_t stream) {
    const float* x    = (const float*)d_in[0];
    const int*   ei   = (const int*)d_in[1];   // [2,E] int32 (harness converts int64)
    const float* W1   = (const float*)d_in[2];
    const float* b1   = (const float*)d_in[3];
    const float* W2   = (const float*)d_in[4];
    const float* b2   = (const float*)d_in[5];
    const float* temp = (const float*)d_in[6];
    float* out = (float*)d_out;

    char* p = (char*)d_ws;
    auto carve = [&](size_t bytes) -> char* {
        char* r = p;
        p += (bytes + 255) & ~(size_t)255;
        return r;
    };
    float* cur    = (float*)carve(sizeof(float) * (size_t)NN * 64);
    float* nxt    = (float*)carve(sizeof(float) * (size_t)NN * 64);
    uint2* packed = (uint2*)carve(sizeof(uint2) * (size_t)EE);
    int* counts   = (int*)carve(sizeof(int) * NN);
    int* cursor   = (int*)carve(sizeof(int) * NN);
    int* offs     = (int*)carve(sizeof(int) * (NN + 1));
    int* partial  = (int*)carve(sizeof(int) * 512);
    float* dinv   = (float*)carve(sizeof(float) * NN);
    short* W1p    = (short*)carve(sizeof(short) * INF * HIDF);
    short* W2p    = (short*)carve(sizeof(short) * HIDF * OUTF);

    const int NB = (NN + 255) / 256;      // 391

    zero_kernel<<<NB, 256, 0, stream>>>(counts, NN);
    zero_kernel<<<NB, 256, 0, stream>>>(cursor, NN);
    pack_w1<<<(INF * HIDF + 255) / 256, 256, 0, stream>>>(W1, W1p);
    pack_w2<<<(HIDF * OUTF + 255) / 256, 256, 0, stream>>>(W2, W2p);

    count_kernel<<<EE / 256, 256, 0, stream>>>(ei, counts);
    dinv_kernel<<<NB, 256, 0, stream>>>(counts, dinv);
    scan1<<<NB, 256, 0, stream>>>(counts, offs, partial);
    scan2<<<1, 512, 0, stream>>>(partial, NB);
    scan3<<<(NN + 256) / 256, 256, 0, stream>>>(offs, partial);
    fill_kernel<<<EE / 256, 256, 0, stream>>>(ei, offs, cursor, dinv, packed);

    mlp_kernel<<<(NN + 63) / 64, 256, 0, stream>>>(x, W1p, W2p, b1, b2, temp, cur, out);

    float* a = cur;
    float* b = nxt;
    for (int k = 1; k <= KSTEPS; k++) {
        prop_kernel<<<NN / 4, 256, 0, stream>>>(packed, offs, dinv, a, b, out, temp, k);
        float* t = a; a = b; b = t;
    }
}

// Round 2
// 1426.983 us; speedup vs baseline: 1.3382x; 1.3382x over previous
//
#include <hip/hip_runtime.h>
#include <hip/hip_bf16.h>

#define NN   100000
#define EE   3200000
#define INF  512
#define HIDF 256
#define OUTF 64
#define KSTEPS 10

typedef __attribute__((ext_vector_type(8))) short short8;
typedef __attribute__((ext_vector_type(4))) float floatx4;
typedef unsigned short ushort_t;

static __device__ inline short bf2s(__hip_bfloat16 h) {
    return __builtin_bit_cast(short, h);
}

// manual round-to-nearest-even f32 -> bf16 (finite inputs)
static __device__ inline unsigned short f2bf(float f) {
    unsigned u = __float_as_uint(f);
    unsigned r = (u + 0x7FFFu + ((u >> 16) & 1u)) >> 16;
    return (unsigned short)r;
}

static __device__ inline float b2f(unsigned short u) {
    return __uint_as_float(((unsigned)u) << 16);
}

// ---------------- setup kernels ----------------

__global__ void zero_kernel(int* p, int n) {
    int i = blockIdx.x * 256 + threadIdx.x;
    if (i < n) p[i] = 0;
}

__global__ void count_kernel(const int* __restrict__ ei, int* __restrict__ counts) {
    int e = blockIdx.x * 256 + threadIdx.x;
    if (e < EE) atomicAdd(&counts[ei[EE + e]], 1);
}

__global__ void dinv_kernel(const int* __restrict__ counts, float* __restrict__ dinv) {
    int i = blockIdx.x * 256 + threadIdx.x;
    if (i < NN) dinv[i] = rsqrtf((float)(counts[i] + 1));  // +1 self loop
}

// chunk=256 exclusive scan, per-block
__global__ void scan1(const int* __restrict__ counts, int* __restrict__ offs,
                      int* __restrict__ partial) {
    __shared__ int s[256];
    int tid = threadIdx.x;
    int i = blockIdx.x * 256 + tid;
    int v = (i < NN) ? counts[i] : 0;
    s[tid] = v;
    __syncthreads();
    for (int d = 1; d < 256; d <<= 1) {
        int t = (tid >= d) ? s[tid - d] : 0;
        __syncthreads();
        s[tid] += t;
        __syncthreads();
    }
    if (i < NN) offs[i] = s[tid] - v;     // exclusive within block
    if (tid == 255) partial[blockIdx.x] = s[255];
}

__global__ void scan2(int* partial, int nblocks) {
    __shared__ int s[512];
    int tid = threadIdx.x;
    int v = (tid < nblocks) ? partial[tid] : 0;
    s[tid] = v;
    __syncthreads();
    for (int d = 1; d < 512; d <<= 1) {
        int t = (tid >= d) ? s[tid - d] : 0;
        __syncthreads();
        s[tid] += t;
        __syncthreads();
    }
    if (tid < nblocks) partial[tid] = s[tid] - v;  // exclusive block bases
}

__global__ void scan3(int* __restrict__ offs, const int* __restrict__ partial) {
    int i = blockIdx.x * 256 + threadIdx.x;
    if (i < NN) offs[i] += partial[i >> 8];
    else if (i == NN) offs[NN] = EE;
}

// countdown-fill: reuses counts[] as cursor (counts destroyed here)
__global__ void fill_kernel(const int* __restrict__ ei, const int* __restrict__ offs,
                            int* __restrict__ counts, int* __restrict__ srcIdx) {
    int e = blockIdx.x * 256 + threadIdx.x;
    if (e >= EE) return;
    int r = ei[e];        // source (gathered from)
    int c = ei[EE + e];   // target (aggregated into)
    int old = atomicSub(&counts[c], 1);
    srcIdx[offs[c] + old - 1] = r;
}

// pack W1 into per-lane MFMA B-fragment order:
// dst[((kk*16+t)*64 + q*16 + l)*8 + jj] = bf16(W1[kk*32+q*8+jj][t*16+l])
__global__ void pack_w1(const float* __restrict__ W1, short* __restrict__ W1p) {
    int id = blockIdx.x * 256 + threadIdx.x;
    if (id >= INF * HIDF) return;
    int jj = id & 7, l = (id >> 3) & 15, q = (id >> 7) & 3, t = (id >> 9) & 15, kk = id >> 13;
    int k = kk * 32 + q * 8 + jj, n = t * 16 + l;
    W1p[id] = (short)f2bf(W1[k * HIDF + n]);
}

__global__ void pack_w2(const float* __restrict__ W2, short* __restrict__ W2p) {
    int id = blockIdx.x * 256 + threadIdx.x;
    if (id >= HIDF * OUTF) return;
    int jj = id & 7, l = (id >> 3) & 15, q = (id >> 7) & 3, t = (id >> 9) & 3, kk = id >> 11;
    int k = kk * 32 + q * 8 + jj, n = t * 16 + l;
    W2p[id] = (short)f2bf(W2[k * OUTF + n]);
}

// ---------------- fused MLP: h = relu(x@W1+b1)@W2+b2 ----------------
// writes z0 = bf16(dinv*h) and out = temp[0]*h

__global__ __launch_bounds__(256) void mlp_kernel(
    const float* __restrict__ x, const short* __restrict__ W1p,
    const short* __restrict__ W2p, const float* __restrict__ b1,
    const float* __restrict__ b2, const float* __restrict__ temp,
    const float* __restrict__ dinv,
    ushort_t* __restrict__ z0, float* __restrict__ out) {

    __shared__ __align__(16) short hlds[64][HIDF + 8];

    int tid = threadIdx.x;
    int wave = tid >> 6, lane = tid & 63;
    int l16 = lane & 15, quad = lane >> 4;
    int brow = blockIdx.x * 64;

    const floatx4 zf = {0.f, 0.f, 0.f, 0.f};
    floatx4 acc[4][4];
#pragma unroll
    for (int mi = 0; mi < 4; mi++)
#pragma unroll
        for (int j = 0; j < 4; j++) acc[mi][j] = zf;

    // row base pointers (clamped for tail block; stores masked later)
    const float* rp[4];
#pragma unroll
    for (int mi = 0; mi < 4; mi++) {
        int row = brow + mi * 16 + l16;
        if (row > NN - 1) row = NN - 1;
        rp[mi] = x + (size_t)row * INF + quad * 8;
    }

    // GEMM1: rows [brow,brow+64) x cols [wave*64, wave*64+64), K=512
    for (int kk = 0; kk < 16; kk++) {
        short8 a[4];
#pragma unroll
        for (int mi = 0; mi < 4; mi++) {
            const float4* ap = reinterpret_cast<const float4*>(rp[mi] + kk * 32);
            float4 f0 = ap[0];
            float4 f1 = ap[1];
            __hip_bfloat162 q0 = __float22bfloat162_rn(make_float2(f0.x, f0.y));
            __hip_bfloat162 q1 = __float22bfloat162_rn(make_float2(f0.z, f0.w));
            __hip_bfloat162 q2 = __float22bfloat162_rn(make_float2(f1.x, f1.y));
            __hip_bfloat162 q3 = __float22bfloat162_rn(make_float2(f1.z, f1.w));
            short8 av;
            av[0] = bf2s(q0.x); av[1] = bf2s(q0.y);
            av[2] = bf2s(q1.x); av[3] = bf2s(q1.y);
            av[4] = bf2s(q2.x); av[5] = bf2s(q2.y);
            av[6] = bf2s(q3.x); av[7] = bf2s(q3.y);
            a[mi] = av;
        }
        short8 b[4];
#pragma unroll
        for (int j = 0; j < 4; j++) {
            int t = wave * 4 + j;
            b[j] = *reinterpret_cast<const short8*>(
                W1p + (((size_t)(kk * 16 + t) * 64 + quad * 16 + l16) << 3));
        }
#pragma unroll
        for (int mi = 0; mi < 4; mi++)
#pragma unroll
            for (int j = 0; j < 4; j++)
                acc[mi][j] = __builtin_amdgcn_mfma_f32_16x16x32_bf16(a[mi], b[j], acc[mi][j], 0, 0, 0);
    }

    // bias + relu -> LDS (bf16), C-layout: D[row=quad*4+r][col=l16]
#pragma unroll
    for (int j = 0; j < 4; j++) {
        float bj = b1[wave * 64 + j * 16 + l16];
#pragma unroll
        for (int mi = 0; mi < 4; mi++)
#pragma unroll
            for (int r = 0; r < 4; r++) {
                float v = acc[mi][j][r] + bj;
                v = fmaxf(v, 0.f);
                hlds[mi * 16 + quad * 4 + r][wave * 64 + j * 16 + l16] = (short)f2bf(v);
            }
    }
    __syncthreads();

    // GEMM2: wave handles rows [wave*16, wave*16+16) x 64 out cols, K=256
    floatx4 acc2[4];
#pragma unroll
    for (int j = 0; j < 4; j++) acc2[j] = zf;

#pragma unroll
    for (int kk = 0; kk < 8; kk++) {
        short8 a2 = *reinterpret_cast<const short8*>(&hlds[wave * 16 + l16][kk * 32 + quad * 8]);
#pragma unroll
        for (int j = 0; j < 4; j++) {
            short8 bb = *reinterpret_cast<const short8*>(
                W2p + (((size_t)(kk * 4 + j) * 64 + quad * 16 + l16) << 3));
            acc2[j] = __builtin_amdgcn_mfma_f32_16x16x32_bf16(a2, bb, acc2[j], 0, 0, 0);
        }
    }

    float t0 = temp[0];
#pragma unroll
    for (int j = 0; j < 4; j++) {
        float bb = b2[j * 16 + l16];
#pragma unroll
        for (int r = 0; r < 4; r++) {
            int row = brow + wave * 16 + quad * 4 + r;
            if (row < NN) {
                float v = acc2[j][r] + bb;
                size_t o = (size_t)row * 64 + j * 16 + l16;
                out[o] = t0 * v;
                z0[o] = f2bf(dinv[row] * v);
            }
        }
    }
}

// ---------------- propagation: one wave per target node, lane = feature ------
// z = dinv .* cur (bf16).  acc = z[self] + sum z[src];
// z' = dinv^2*acc (bf16);  hid += gamma*dinv*acc.

__global__ __launch_bounds__(256) void prop_kernel(
    const int* __restrict__ srcIdx, const int* __restrict__ offs,
    const float* __restrict__ dinv, const ushort_t* __restrict__ z,
    ushort_t* __restrict__ zn, float* __restrict__ hid,
    const float* __restrict__ temp, int k, int write_z) {

    int node = blockIdx.x * 4 + (threadIdx.x >> 6);
    if (node >= NN) return;
    int f = threadIdx.x & 63;
    int beg = __builtin_amdgcn_readfirstlane(offs[node]);
    int end = __builtin_amdgcn_readfirstlane(offs[node + 1]);
    size_t o = (size_t)node * 64 + f;
    float acc = b2f(z[o]);   // self loop term (z[c])

    int e = beg;
    for (; e + 4 <= end; e += 4) {
        int s0 = srcIdx[e];
        int s1 = srcIdx[e + 1];
        int s2 = srcIdx[e + 2];
        int s3 = srcIdx[e + 3];
        float v0 = b2f(z[(size_t)s0 * 64 + f]);
        float v1 = b2f(z[(size_t)s1 * 64 + f]);
        float v2 = b2f(z[(size_t)s2 * 64 + f]);
        float v3 = b2f(z[(size_t)s3 * 64 + f]);
        acc += v0 + v1 + v2 + v3;
    }
    for (; e < end; ++e) {
        acc += b2f(z[(size_t)srcIdx[e] * 64 + f]);
    }

    float dv = dinv[node];
    float cn = dv * acc;                 // cur_next
    hid[o] += temp[k] * cn;
    if (write_z) zn[o] = f2bf(dv * cn);  // z_next = dinv * cur_next
}

// ---------------- launch ----------------

extern "C" void kernel_launch(void* const* d_in, const int* in_sizes, int n_in,
                              void* d_out, int out_size, void* d_ws, size_t ws_size,
                              hipStream_t stream) {
    const float* x    = (const float*)d_in[0];
    const int*   ei   = (const int*)d_in[1];   // [2,E] int32 (harness converts int64)
    const float* W1   = (const float*)d_in[2];
    const float* b1   = (const float*)d_in[3];
    const float* W2   = (const float*)d_in[4];
    const float* b2   = (const float*)d_in[5];
    const float* temp = (const float*)d_in[6];
    float* out = (float*)d_out;

    char* p = (char*)d_ws;
    auto carve = [&](size_t bytes) -> char* {
        char* r = p;
        p += (bytes + 255) & ~(size_t)255;
        return r;
    };
    ushort_t* zA   = (ushort_t*)carve(sizeof(ushort_t) * (size_t)NN * 64);
    ushort_t* zB   = (ushort_t*)carve(sizeof(ushort_t) * (size_t)NN * 64);
    int* srcIdx    = (int*)carve(sizeof(int) * (size_t)EE);
    int* counts    = (int*)carve(sizeof(int) * NN);
    int* offs      = (int*)carve(sizeof(int) * (NN + 1));
    int* partial   = (int*)carve(sizeof(int) * 512);
    float* dinv    = (float*)carve(sizeof(float) * NN);
    short* W1p     = (short*)carve(sizeof(short) * INF * HIDF);
    short* W2p     = (short*)carve(sizeof(short) * HIDF * OUTF);

    const int NB = (NN + 255) / 256;      // 391

    zero_kernel<<<NB, 256, 0, stream>>>(counts, NN);
    pack_w1<<<(INF * HIDF + 255) / 256, 256, 0, stream>>>(W1, W1p);
    pack_w2<<<(HIDF * OUTF + 255) / 256, 256, 0, stream>>>(W2, W2p);

    count_kernel<<<EE / 256, 256, 0, stream>>>(ei, counts);
    dinv_kernel<<<NB, 256, 0, stream>>>(counts, dinv);
    scan1<<<NB, 256, 0, stream>>>(counts, offs, partial);
    scan2<<<1, 512, 0, stream>>>(partial, NB);
    scan3<<<(NN + 256) / 256, 256, 0, stream>>>(offs, partial);
    fill_kernel<<<EE / 256, 256, 0, stream>>>(ei, offs, counts, srcIdx);

    mlp_kernel<<<(NN + 63) / 64, 256, 0, stream>>>(x, W1p, W2p, b1, b2, temp, dinv, zA, out);

    ushort_t* a = zA;
    ushort_t* b = zB;
    for (int k = 1; k <= KSTEPS; k++) {
        prop_kernel<<<NN / 4, 256, 0, stream>>>(srcIdx, offs, dinv, a, b, out, temp, k,
                                                (k < KSTEPS) ? 1 : 0);
        ushort_t* t = a; a = b; b = t;
    }
}